// Round 6
// baseline (291.112 us; speedup 1.0000x reference)
//
#include <hip/hip_runtime.h>
#include <math.h>

#define B 64
#define H 40
#define W 40
#define A 5
#define C 80
#define NBOX (H*W*A)          // 8000
#define FEAT (5+C)            // 85
#define MAXB 100
#define SCORE_THR 0.001f
#define IOU_THR 0.5f

#define DEC_BOXES 64          // 64 boxes / 64 threads, single-wave blocks
#define DEC_THREADS 64
#define TILE_B4 1360          // float4s of real data per tile (64*85/4)
#define BUFB 22528            // bytes per LDS buffer half (22*1024, incl. pad)
#define NT ((B*NBOX)/DEC_BOXES)   // 8000 tiles
#define GRIDN 768             // persistent blocks: 256 CU x 3 (45KB dbuf LDS)

#define HBINS 10240           // float bits >>13, scores in (0.001, 1)
#define BINBASE 119808        // 0x3A800000 >> 13
#define TARGET 512            // candidate prefix size (validated R3-R5)

#define BK 48                 // per-(img,class) bucket capacity (avg 6.4)
#define RCAP 1024             // rank-stage survivor cap (candidates <= ~520)

typedef unsigned long long u64;
typedef unsigned int u32;

// ---------------------------------------------------------------- decode ----
// Persistent single-wave blocks, double-buffered global_load_lds (T3 minimum
// 2-phase): per iteration, STAGE(tile t+GRIDN -> buf^1) is issued BEFORE
// compute(tile t, buf), so the 22 HBM->LDS loads fly under ~1500-2500 cyc of
// exp/softmax work; the barrier after compute is where the vmcnt drain lands.
// Compute block is verbatim from the absmax-0 lineage (bit-exact).
__global__ __launch_bounds__(DEC_THREADS) void decode_kernel(
    const float* __restrict__ pred, const float* __restrict__ anchors,
    float* __restrict__ boxes_ws, float* __restrict__ s_ws, int* __restrict__ cls_ws)
{
    __shared__ float lds[2 * BUFB / 4];       // 45056 B -> 3 blocks/CU
    const int tid = threadIdx.x;
    const long long TOT4 = (long long)NT * TILE_B4;

    const float4* src4 = (const float4*)pred;
    // stage tile t into buffer half h: 22 x global_load_lds dwordx4.
    // LDS dest = wave-uniform base + lane*16 (linear). Global src per-lane,
    // clamped at buffer end (last tile): garbage lands in LDS pad, never read.
    auto stage = [&](int t, int h) {
        const long long base4 = (long long)t * TILE_B4;
        #pragma unroll
        for (int i = 0; i < 22; ++i) {
            long long g4 = base4 + i*64 + tid;
            if (g4 >= TOT4) g4 = TOT4 - 1;
            __builtin_amdgcn_global_load_lds(
                (const __attribute__((address_space(1))) void*)(src4 + g4),
                (__attribute__((address_space(3))) void*)((char*)lds + h*BUFB + i*1024),
                16, 0, 0);
        }
    };

    int cur = 0;
    int t = blockIdx.x;
    if (t < NT) stage(t, 0);
    __syncthreads();                          // drain prologue stage

    while (t < NT) {
        const int tn = t + GRIDN;
        if (tn < NT) stage(tn, cur ^ 1);      // prefetch next tile (flies under compute)

        // ---------------- compute tile t from buf[cur] (verbatim) ----------
        const float* l = lds + (cur * (BUFB/4)) + tid * FEAT;  // stride 85: 2-way alias, free
        const int box = t * DEC_BOXES + tid;

        int img  = box / NBOX;
        int n    = box - img * NBOX;
        int cell = n / A;
        int a    = n - cell * A;
        int gx   = cell % W;
        int gy   = cell / W;

        float tx = l[0], ty = l[1], tw = l[2], th = l[3], tc = l[4];

        float lg[C];
        #pragma unroll
        for (int i = 0; i < C; ++i) lg[i] = l[5+i];

        float sx = 1.f / (1.f + expf(-tx));
        float sy = 1.f / (1.f + expf(-ty));
        float cx = (sx + (float)gx) / (float)W;
        float cy = (sy + (float)gy) / (float)H;
        float aw = anchors[a*2+0], ah = anchors[a*2+1];
        float bw = expf(tw) * aw / (float)W;
        float bh = expf(th) * ah / (float)H;
        float conf = 1.f / (1.f + expf(-tc));

        // max: 8-accumulator tree (fmax exactly associative)
        float mm[8];
        #pragma unroll
        for (int w = 0; w < 8; ++w) mm[w] = lg[w];
        #pragma unroll
        for (int i = 8; i < C; ++i) mm[i & 7] = fmaxf(mm[i & 7], lg[i]);
        float m = fmaxf(fmaxf(fmaxf(mm[0],mm[1]),fmaxf(mm[2],mm[3])),
                        fmaxf(fmaxf(mm[4],mm[5]),fmaxf(mm[6],mm[7])));

        // sequential ascending exp-sum: preserves fold-left order (bit-exact)
        float sum = 0.f;
        float bv[4] = {-1.f,-1.f,-1.f,-1.f};
        int   bi[4] = {0,0,0,0};
        #pragma unroll
        for (int i = 0; i < C; ++i) {
            float e = expf(lg[i] - m);
            sum += e;
            int w = i & 3;
            if (e > bv[w]) { bv[w] = e; bi[w] = i; }
        }
        float best_e = bv[0]; int best_c = bi[0];
        #pragma unroll
        for (int w = 1; w < 4; ++w) {
            if (bv[w] > best_e || (bv[w] == best_e && bi[w] < best_c)) { best_e = bv[w]; best_c = bi[w]; }
        }

        float score = conf * (best_e / sum);
        float s0 = (score > SCORE_THR) ? score : -1.0f;

        float x1 = cx - bw*0.5f, y1 = cy - bh*0.5f;
        float x2 = cx + bw*0.5f, y2 = cy + bh*0.5f;

        ((float4*)boxes_ws)[box] = make_float4(x1, y1, x2, y2);
        s_ws[box] = s0;
        cls_ws[box] = best_c;
        // -------------------------------------------------------------------

        __syncthreads();   // vmcnt drain for the prefetched tile + LDS reuse fence
        cur ^= 1;
        t = tn;
    }
}

// -------------------------------------------------- fused select+NMS+rank ----
// One block (1024 thr, 16 waves) per image. Phases, all in 41KB LDS:
//   1. histogram of score bits (LDS, R0-proven)
//   2. scan from top -> threshold bin tb (whole-bin inclusion => genuine rank
//      prefix incl. ties; sub-prefix keys are strictly smaller so they cannot
//      affect prefix members' survivor status)
//   3. scatter prefix candidates into per-class LDS key buckets (hist region
//      reused; boxes NOT stored -- the key's idx field recovers them)
//   4. per-class greedy DPP-NMS, 16 waves x 5 classes, survivors in-place
//   5. compact + O(m^2) rank (m ~ 500) + output
// key = [score_bits:30 @32][NBOX-idx:13 @19][bucket_pos:6 @13][cls:7 @0]
// ordered by (score desc, idx asc); pos/cls sit below idx -> atomic arrival
// order cannot perturb selection semantics.
__device__ __forceinline__ u64 wave_max_u64(u64 v) {
    // DPP full-wave max (validated R4/R5). Keys >= 0, 0 is the identity.
    #define STAGE(CTRL, RMASK) { \
        u32 lo = (u32)v, hi = (u32)(v >> 32); \
        u32 tlo = (u32)__builtin_amdgcn_update_dpp(0, (int)lo, CTRL, RMASK, 0xf, true); \
        u32 thi = (u32)__builtin_amdgcn_update_dpp(0, (int)hi, CTRL, RMASK, 0xf, true); \
        u64 t = ((u64)thi << 32) | (u64)tlo; \
        if (t > v) v = t; \
    }
    STAGE(0x111, 0xf)   // row_shr:1
    STAGE(0x112, 0xf)   // row_shr:2
    STAGE(0x114, 0xf)   // row_shr:4
    STAGE(0x118, 0xf)   // row_shr:8
    STAGE(0x142, 0xa)   // row_bcast15
    STAGE(0x143, 0xc)   // row_bcast31; lane 63 = global max
    #undef STAGE
    u32 flo = (u32)__builtin_amdgcn_readlane((int)(u32)v, 63);
    u32 fhi = (u32)__builtin_amdgcn_readlane((int)(v >> 32), 63);
    return ((u64)fhi << 32) | (u64)flo;
}

__global__ __launch_bounds__(1024) void selnmsrank_kernel(
    const float* __restrict__ boxes_ws, const float* __restrict__ s_ws,
    const int* __restrict__ cls_ws, float* __restrict__ out)
{
    // one 40KB region, phase-overlaid:
    //   phase 1-2: hist[10240] ints            @ 0     .. 40960
    //   phase 3+ : bkey[C*BK=3840] u64         @ 0     .. 30720
    //              ckeys[RCAP=1024] u64        @ 30720 .. 38912
    //              bcnt[C] ints                @ 38912 .. 39232
    __shared__ __align__(16) char smem[HBINS * 4];
    int* hist  = (int*)smem;
    u64* bkey  = (u64*)smem;
    u64* ckeys = (u64*)(smem + 30720);
    int* bcnt  = (int*)(smem + 38912);
    __shared__ int wavesum[16];
    __shared__ int tbin_s;
    __shared__ int cnt;

    const int img  = blockIdx.x;
    const int tid  = threadIdx.x;
    const int lane = tid & 63;
    const int wid  = tid >> 6;
    const long long ib = (long long)img * NBOX;

    // ---- phase 1: histogram ----
    #pragma unroll
    for (int q = 0; q < HBINS/1024; ++q) hist[tid + q*1024] = 0;
    if (tid == 0) { tbin_s = 0; cnt = 0; }
    __syncthreads();

    float sc_r[8];
    #pragma unroll
    for (int k = 0; k < 8; ++k) {
        int j = tid + k*1024;
        float s = (j < NBOX) ? s_ws[ib + j] : -1.f;
        sc_r[k] = s;
        if (s > 0.f) {
            int b = (int)(__float_as_uint(s) >> 13) - BINBASE;
            b = max(0, min(HBINS-1, b));
            atomicAdd(&hist[b], 1);
        }
    }
    __syncthreads();

    // ---- phase 2: threshold bin (thread tid owns tid-th 10-bin chunk
    //      FROM THE TOP) ----
    int sum_r = 0;
    {
        int base = HBINS - 10*(tid+1);
        #pragma unroll
        for (int q = 0; q < 10; ++q) sum_r += hist[base + q];
    }
    int incl = sum_r;
    #pragma unroll
    for (int off = 1; off < 64; off <<= 1) {
        int o = __shfl_up(incl, off);
        if (lane >= off) incl += o;
    }
    if (lane == 63) wavesum[wid] = incl;
    __syncthreads();
    {
        int wbase = 0;
        for (int w = 0; w < wid; ++w) wbase += wavesum[w];
        int excl = wbase + incl - sum_r;
        if (excl < TARGET && excl + sum_r >= TARGET) {
            int cum = excl;
            for (int q = 0; q < 10; ++q) {
                int b = HBINS - 10*tid - 1 - q;
                cum += hist[b];
                if (cum >= TARGET) { tbin_s = b; break; }
            }
        }
    }
    __syncthreads();           // hist dead beyond this point
    const int tb = tbin_s;

    if (tid < C) bcnt[tid] = 0;
    __syncthreads();

    // ---- phase 3: scatter prefix candidates into LDS key buckets ----
    #pragma unroll
    for (int k = 0; k < 8; ++k) {
        int j = tid + k*1024;
        float s = sc_r[k];
        if (j < NBOX && s > 0.f) {
            int b = (int)(__float_as_uint(s) >> 13) - BINBASE;
            b = max(0, min(HBINS-1, b));
            if (b >= tb) {
                int c = cls_ws[ib + j];
                int pos = atomicAdd(&bcnt[c], 1);
                if (pos < BK) {
                    u64 key = ((u64)__float_as_uint(s) << 32)
                            | ((u64)(NBOX - j) << 19)
                            | ((u64)pos << 13) | (u64)c;
                    bkey[c*BK + pos] = key;
                }
            }
        }
    }
    __syncthreads();

    // ---- phase 4: per-class greedy NMS, 16 waves x 5 classes each ----
    for (int q = 0; q < 5; ++q) {
        const int c  = wid*5 + q;
        const int nb = min(bcnt[c], BK);

        u64 key = 0, keep = 0;
        float x1=0.f, y1=0.f, x2=0.f, y2=0.f, ar=0.f;
        if (lane < nb) {
            key = bkey[c*BK + lane];
            int bidx = NBOX - (int)((key >> 19) & 0x1FFF);
            float4 b4 = ((const float4*)boxes_ws)[ib + bidx];
            x1=b4.x; y1=b4.y; x2=b4.z; y2=b4.w;
            ar = fmaxf(x2-x1,0.f)*fmaxf(y2-y1,0.f);
        }

        for (int t = 0; t < BK; ++t) {
            u64 bk = wave_max_u64(key);
            if (bk == 0) break;
            int sl = (int)((bk >> 13) & 63);
            float sx1 = __shfl(x1, sl), sy1 = __shfl(y1, sl);
            float sx2 = __shfl(x2, sl), sy2 = __shfl(y2, sl);
            float sarea = fmaxf(sx2-sx1,0.f)*fmaxf(sy2-sy1,0.f);

            if (lane == sl) {
                keep = key;                    // survivor, recorded locally
                key = 0;
            } else if (key != 0) {
                float ix1 = fmaxf(sx1, x1);
                float iy1 = fmaxf(sy1, y1);
                float ix2 = fminf(sx2, x2);
                float iy2 = fminf(sy2, y2);
                float inter = fmaxf(ix2-ix1,0.f)*fmaxf(iy2-iy1,0.f);
                float iou = inter / (ar + sarea - inter + 1e-8f);
                if (iou > IOU_THR) key = 0;    // same class by construction
            }
        }

        // in-place survivor write (wave owns this class row; also clears)
        if (lane < BK) bkey[c*BK + lane] = keep;
    }
    __syncthreads();

    // ---- phase 5: compact nonzero survivors, rank by key desc, output ----
    for (int i = tid; i < C*BK; i += 1024) {
        u64 k = bkey[i];
        if (k != 0) {
            int p = atomicAdd(&cnt, 1);       // LDS atomic: cheap
            if (p < RCAP) ckeys[p] = k;
        }
    }
    __syncthreads();
    const int m = min(cnt, RCAP);

    float* out_boxes  = out;                  // [B,100,4]
    float* out_scores = out + B*MAXB*4;       // [B,100]
    float* out_cls    = out + B*MAXB*5;       // [B,100]

    for (int i = tid; i < m; i += 1024) {
        u64 mine = ckeys[i];
        int r = 0;
        for (int j = 0; j < m; ++j) r += (ckeys[j] > mine) ? 1 : 0;  // broadcast
        if (r < MAXB) {
            int c    = (int)(mine & 127);
            int bidx = NBOX - (int)((mine >> 19) & 0x1FFF);
            float4 b4 = ((const float4*)boxes_ws)[ib + bidx];
            int o = img*MAXB + r;
            out_boxes[o*4+0] = b4.x; out_boxes[o*4+1] = b4.y;
            out_boxes[o*4+2] = b4.z; out_boxes[o*4+3] = b4.w;
            out_scores[o] = __uint_as_float((u32)(mine >> 32));
            out_cls[o]    = (float)c;
        }
    }

    // tail: box=0, score=0, class=-1
    int base = min(m, MAXB);
    for (int r = base + tid; r < MAXB; r += 1024) {
        int o = img*MAXB + r;
        out_boxes[o*4+0]=0.f; out_boxes[o*4+1]=0.f;
        out_boxes[o*4+2]=0.f; out_boxes[o*4+3]=0.f;
        out_scores[o]=0.f;
        out_cls[o]=-1.f;
    }
}

// ---------------------------------------------------------------- launch ----
extern "C" void kernel_launch(void* const* d_in, const int* in_sizes, int n_in,
                              void* d_out, int out_size, void* d_ws, size_t ws_size,
                              hipStream_t stream) {
    const float* pred    = (const float*)d_in[0];   // [64,40,40,425] f32
    const float* anchors = (const float*)d_in[1];   // [5,2] f32
    float* out = (float*)d_out;                     // 38400 f32

    char* p = (char*)d_ws;
    float*  boxes_ws  = (float*)p;              p += (size_t)B*NBOX*4*sizeof(float);   // 8.19 MB
    float*  s_ws      = (float*)p;              p += (size_t)B*NBOX*sizeof(float);     // 2.05 MB
    int*    cls_ws    = (int*)p;                /* 2.05 MB; total 12.3 MB */

    decode_kernel<<<GRIDN, DEC_THREADS, 0, stream>>>(
        pred, anchors, boxes_ws, s_ws, cls_ws);
    selnmsrank_kernel<<<B, 1024, 0, stream>>>(
        boxes_ws, s_ws, cls_ws, out);
}

// Round 7
// 285.735 us; speedup vs baseline: 1.0188x; 1.0188x over previous
//
#include <hip/hip_runtime.h>
#include <math.h>

#define B 64
#define H 40
#define W 40
#define A 5
#define C 80
#define NBOX (H*W*A)          // 8000
#define FEAT (5+C)            // 85
#define MAXB 100
#define SCORE_THR 0.001f
#define IOU_THR 0.5f

#define DEC_THREADS 256       // 4 waves/block, no LDS, no barrier

#define HBINS 10240           // float bits >>13, scores in (0.001, 1)
#define BINBASE 119808        // 0x3A800000 >> 13
#define TARGET 512            // candidate prefix size (validated R3-R5)

#define BK 48                 // per-(img,class) bucket capacity (avg 6.4)
#define RCAP 1024             // rank-stage survivor cap (candidates <= ~520)

typedef unsigned long long u64;
typedef unsigned int u32;

// ---------------------------------------------------------------- decode ----
// LDS-free decode: each thread reads its OWN 340B row directly from global
// into registers (85 floats, compile-time indices). Per-instruction lane
// coalescing is poor (stride 340B) but every 64B line is fully consumed by
// one lane's consecutive loads (L1-resident) -> HBM traffic unchanged.
// What this buys: no 22.5KB/wave LDS wall (7 waves/CU -> VGPR-bound ~16
// waves/CU), no __syncthreads vmcnt(0) cliff, 85 independent loads in
// flight per thread. Compute block is verbatim from the absmax-0 lineage:
// identical values consumed in identical order (v[i] == old l[i]).
__global__ __launch_bounds__(DEC_THREADS) void decode_kernel(
    const float* __restrict__ pred, const float* __restrict__ anchors,
    float* __restrict__ boxes_ws, float* __restrict__ s_ws, int* __restrict__ cls_ws)
{
    const int box = blockIdx.x * DEC_THREADS + threadIdx.x;   // grid covers B*NBOX
    const float* __restrict__ r = pred + (long long)box * FEAT;

    float v[FEAT];            // full row in registers; all indices compile-time
    #pragma unroll
    for (int i = 0; i < FEAT; ++i) v[i] = r[i];

    int img  = box / NBOX;
    int n    = box - img * NBOX;
    int cell = n / A;
    int a    = n - cell * A;
    int gx   = cell % W;
    int gy   = cell / W;

    float tx = v[0], ty = v[1], tw = v[2], th = v[3], tc = v[4];

    float sx = 1.f / (1.f + expf(-tx));
    float sy = 1.f / (1.f + expf(-ty));
    float cx = (sx + (float)gx) / (float)W;
    float cy = (sy + (float)gy) / (float)H;
    float aw = anchors[a*2+0], ah = anchors[a*2+1];
    float bw = expf(tw) * aw / (float)W;
    float bh = expf(th) * ah / (float)H;
    float conf = 1.f / (1.f + expf(-tc));

    // max: 8-accumulator tree (fmax exactly associative)
    float mm[8];
    #pragma unroll
    for (int w = 0; w < 8; ++w) mm[w] = v[5+w];
    #pragma unroll
    for (int i = 8; i < C; ++i) mm[i & 7] = fmaxf(mm[i & 7], v[5+i]);
    float m = fmaxf(fmaxf(fmaxf(mm[0],mm[1]),fmaxf(mm[2],mm[3])),
                    fmaxf(fmaxf(mm[4],mm[5]),fmaxf(mm[6],mm[7])));

    // sequential ascending exp-sum: preserves fold-left order (bit-exact)
    float sum = 0.f;
    float bv[4] = {-1.f,-1.f,-1.f,-1.f};
    int   bi[4] = {0,0,0,0};
    #pragma unroll
    for (int i = 0; i < C; ++i) {
        float e = expf(v[5+i] - m);
        sum += e;
        int w = i & 3;
        if (e > bv[w]) { bv[w] = e; bi[w] = i; }
    }
    float best_e = bv[0]; int best_c = bi[0];
    #pragma unroll
    for (int w = 1; w < 4; ++w) {
        if (bv[w] > best_e || (bv[w] == best_e && bi[w] < best_c)) { best_e = bv[w]; best_c = bi[w]; }
    }

    float score = conf * (best_e / sum);
    float s0 = (score > SCORE_THR) ? score : -1.0f;

    float x1 = cx - bw*0.5f, y1 = cy - bh*0.5f;
    float x2 = cx + bw*0.5f, y2 = cy + bh*0.5f;

    ((float4*)boxes_ws)[box] = make_float4(x1, y1, x2, y2);
    s_ws[box] = s0;
    cls_ws[box] = best_c;
}

// -------------------------------------------------- fused select+NMS+rank ----
// One block (1024 thr, 16 waves) per image. Phases, all in 41KB LDS:
//   1. histogram of score bits (LDS, R0-proven)
//   2. scan from top -> threshold bin tb (whole-bin inclusion => genuine rank
//      prefix incl. ties; sub-prefix keys are strictly smaller so they cannot
//      affect prefix members' survivor status)
//   3. scatter prefix candidates into per-class LDS key buckets (hist region
//      reused; boxes NOT stored -- the key's idx field recovers them)
//   4. per-class greedy DPP-NMS, 16 waves x 5 classes, survivors in-place
//   5. compact + O(m^2) rank (m ~ 500) + output
// key = [score_bits:30 @32][NBOX-idx:13 @19][bucket_pos:6 @13][cls:7 @0]
// ordered by (score desc, idx asc); pos/cls sit below idx -> atomic arrival
// order cannot perturb selection semantics.
__device__ __forceinline__ u64 wave_max_u64(u64 v) {
    // DPP full-wave max (validated R4/R5). Keys >= 0, 0 is the identity.
    #define STAGE(CTRL, RMASK) { \
        u32 lo = (u32)v, hi = (u32)(v >> 32); \
        u32 tlo = (u32)__builtin_amdgcn_update_dpp(0, (int)lo, CTRL, RMASK, 0xf, true); \
        u32 thi = (u32)__builtin_amdgcn_update_dpp(0, (int)hi, CTRL, RMASK, 0xf, true); \
        u64 t = ((u64)thi << 32) | (u64)tlo; \
        if (t > v) v = t; \
    }
    STAGE(0x111, 0xf)   // row_shr:1
    STAGE(0x112, 0xf)   // row_shr:2
    STAGE(0x114, 0xf)   // row_shr:4
    STAGE(0x118, 0xf)   // row_shr:8
    STAGE(0x142, 0xa)   // row_bcast15
    STAGE(0x143, 0xc)   // row_bcast31; lane 63 = global max
    #undef STAGE
    u32 flo = (u32)__builtin_amdgcn_readlane((int)(u32)v, 63);
    u32 fhi = (u32)__builtin_amdgcn_readlane((int)(v >> 32), 63);
    return ((u64)fhi << 32) | (u64)flo;
}

__global__ __launch_bounds__(1024) void selnmsrank_kernel(
    const float* __restrict__ boxes_ws, const float* __restrict__ s_ws,
    const int* __restrict__ cls_ws, float* __restrict__ out)
{
    // one 40KB region, phase-overlaid:
    //   phase 1-2: hist[10240] ints            @ 0     .. 40960
    //   phase 3+ : bkey[C*BK=3840] u64         @ 0     .. 30720
    //              ckeys[RCAP=1024] u64        @ 30720 .. 38912
    //              bcnt[C] ints                @ 38912 .. 39232
    __shared__ __align__(16) char smem[HBINS * 4];
    int* hist  = (int*)smem;
    u64* bkey  = (u64*)smem;
    u64* ckeys = (u64*)(smem + 30720);
    int* bcnt  = (int*)(smem + 38912);
    __shared__ int wavesum[16];
    __shared__ int tbin_s;
    __shared__ int cnt;

    const int img  = blockIdx.x;
    const int tid  = threadIdx.x;
    const int lane = tid & 63;
    const int wid  = tid >> 6;
    const long long ib = (long long)img * NBOX;

    // ---- phase 1: histogram ----
    #pragma unroll
    for (int q = 0; q < HBINS/1024; ++q) hist[tid + q*1024] = 0;
    if (tid == 0) { tbin_s = 0; cnt = 0; }
    __syncthreads();

    float sc_r[8];
    #pragma unroll
    for (int k = 0; k < 8; ++k) {
        int j = tid + k*1024;
        float s = (j < NBOX) ? s_ws[ib + j] : -1.f;
        sc_r[k] = s;
        if (s > 0.f) {
            int b = (int)(__float_as_uint(s) >> 13) - BINBASE;
            b = max(0, min(HBINS-1, b));
            atomicAdd(&hist[b], 1);
        }
    }
    __syncthreads();

    // ---- phase 2: threshold bin (thread tid owns tid-th 10-bin chunk
    //      FROM THE TOP) ----
    int sum_r = 0;
    {
        int base = HBINS - 10*(tid+1);
        #pragma unroll
        for (int q = 0; q < 10; ++q) sum_r += hist[base + q];
    }
    int incl = sum_r;
    #pragma unroll
    for (int off = 1; off < 64; off <<= 1) {
        int o = __shfl_up(incl, off);
        if (lane >= off) incl += o;
    }
    if (lane == 63) wavesum[wid] = incl;
    __syncthreads();
    {
        int wbase = 0;
        for (int w = 0; w < wid; ++w) wbase += wavesum[w];
        int excl = wbase + incl - sum_r;
        if (excl < TARGET && excl + sum_r >= TARGET) {
            int cum = excl;
            for (int q = 0; q < 10; ++q) {
                int b = HBINS - 10*tid - 1 - q;
                cum += hist[b];
                if (cum >= TARGET) { tbin_s = b; break; }
            }
        }
    }
    __syncthreads();           // hist dead beyond this point
    const int tb = tbin_s;

    if (tid < C) bcnt[tid] = 0;
    __syncthreads();

    // ---- phase 3: scatter prefix candidates into LDS key buckets ----
    #pragma unroll
    for (int k = 0; k < 8; ++k) {
        int j = tid + k*1024;
        float s = sc_r[k];
        if (j < NBOX && s > 0.f) {
            int b = (int)(__float_as_uint(s) >> 13) - BINBASE;
            b = max(0, min(HBINS-1, b));
            if (b >= tb) {
                int c = cls_ws[ib + j];
                int pos = atomicAdd(&bcnt[c], 1);
                if (pos < BK) {
                    u64 key = ((u64)__float_as_uint(s) << 32)
                            | ((u64)(NBOX - j) << 19)
                            | ((u64)pos << 13) | (u64)c;
                    bkey[c*BK + pos] = key;
                }
            }
        }
    }
    __syncthreads();

    // ---- phase 4: per-class greedy NMS, 16 waves x 5 classes each ----
    for (int q = 0; q < 5; ++q) {
        const int c  = wid*5 + q;
        const int nb = min(bcnt[c], BK);

        u64 key = 0, keep = 0;
        float x1=0.f, y1=0.f, x2=0.f, y2=0.f, ar=0.f;
        if (lane < nb) {
            key = bkey[c*BK + lane];
            int bidx = NBOX - (int)((key >> 19) & 0x1FFF);
            float4 b4 = ((const float4*)boxes_ws)[ib + bidx];
            x1=b4.x; y1=b4.y; x2=b4.z; y2=b4.w;
            ar = fmaxf(x2-x1,0.f)*fmaxf(y2-y1,0.f);
        }

        for (int t = 0; t < BK; ++t) {
            u64 bk = wave_max_u64(key);
            if (bk == 0) break;
            int sl = (int)((bk >> 13) & 63);
            float sx1 = __shfl(x1, sl), sy1 = __shfl(y1, sl);
            float sx2 = __shfl(x2, sl), sy2 = __shfl(y2, sl);
            float sarea = fmaxf(sx2-sx1,0.f)*fmaxf(sy2-sy1,0.f);

            if (lane == sl) {
                keep = key;                    // survivor, recorded locally
                key = 0;
            } else if (key != 0) {
                float ix1 = fmaxf(sx1, x1);
                float iy1 = fmaxf(sy1, y1);
                float ix2 = fminf(sx2, x2);
                float iy2 = fminf(sy2, y2);
                float inter = fmaxf(ix2-ix1,0.f)*fmaxf(iy2-iy1,0.f);
                float iou = inter / (ar + sarea - inter + 1e-8f);
                if (iou > IOU_THR) key = 0;    // same class by construction
            }
        }

        // in-place survivor write (wave owns this class row; also clears)
        if (lane < BK) bkey[c*BK + lane] = keep;
    }
    __syncthreads();

    // ---- phase 5: compact nonzero survivors, rank by key desc, output ----
    for (int i = tid; i < C*BK; i += 1024) {
        u64 k = bkey[i];
        if (k != 0) {
            int p = atomicAdd(&cnt, 1);       // LDS atomic: cheap
            if (p < RCAP) ckeys[p] = k;
        }
    }
    __syncthreads();
    const int m = min(cnt, RCAP);

    float* out_boxes  = out;                  // [B,100,4]
    float* out_scores = out + B*MAXB*4;       // [B,100]
    float* out_cls    = out + B*MAXB*5;       // [B,100]

    for (int i = tid; i < m; i += 1024) {
        u64 mine = ckeys[i];
        int r = 0;
        for (int j = 0; j < m; ++j) r += (ckeys[j] > mine) ? 1 : 0;  // broadcast
        if (r < MAXB) {
            int c    = (int)(mine & 127);
            int bidx = NBOX - (int)((mine >> 19) & 0x1FFF);
            float4 b4 = ((const float4*)boxes_ws)[ib + bidx];
            int o = img*MAXB + r;
            out_boxes[o*4+0] = b4.x; out_boxes[o*4+1] = b4.y;
            out_boxes[o*4+2] = b4.z; out_boxes[o*4+3] = b4.w;
            out_scores[o] = __uint_as_float((u32)(mine >> 32));
            out_cls[o]    = (float)c;
        }
    }

    // tail: box=0, score=0, class=-1
    int base = min(m, MAXB);
    for (int r = base + tid; r < MAXB; r += 1024) {
        int o = img*MAXB + r;
        out_boxes[o*4+0]=0.f; out_boxes[o*4+1]=0.f;
        out_boxes[o*4+2]=0.f; out_boxes[o*4+3]=0.f;
        out_scores[o]=0.f;
        out_cls[o]=-1.f;
    }
}

// ---------------------------------------------------------------- launch ----
extern "C" void kernel_launch(void* const* d_in, const int* in_sizes, int n_in,
                              void* d_out, int out_size, void* d_ws, size_t ws_size,
                              hipStream_t stream) {
    const float* pred    = (const float*)d_in[0];   // [64,40,40,425] f32
    const float* anchors = (const float*)d_in[1];   // [5,2] f32
    float* out = (float*)d_out;                     // 38400 f32

    char* p = (char*)d_ws;
    float*  boxes_ws  = (float*)p;              p += (size_t)B*NBOX*4*sizeof(float);   // 8.19 MB
    float*  s_ws      = (float*)p;              p += (size_t)B*NBOX*sizeof(float);     // 2.05 MB
    int*    cls_ws    = (int*)p;                /* 2.05 MB; total 12.3 MB */

    decode_kernel<<<(B*NBOX)/DEC_THREADS, DEC_THREADS, 0, stream>>>(
        pred, anchors, boxes_ws, s_ws, cls_ws);
    selnmsrank_kernel<<<B, 1024, 0, stream>>>(
        boxes_ws, s_ws, cls_ws, out);
}